// Round 4
// baseline (249.653 us; speedup 1.0000x reference)
//
#include <hip/hip_runtime.h>
#include <hip/hip_bf16.h>
#include <math.h>

// Problem constants
#define B_ROWS 8192
#define N_PTS  16384
#define D_DIM  256

// GEMM tiling
#define BM 128
#define BN 128
#define BK 32
#define KSTEPS (D_DIM / BK)       // 8
#define NSPLIT 16
#define CHUNK  (N_PTS / NSPLIT)   // 1024
#define NTILES (CHUNK / BN)       // 8
#define BTILES (B_ROWS / BM)      // 64
#define GRID_GEMM (BTILES * NSPLIT) // 1024 -> ~3 blocks/CU co-resident

// Folded constants
#define SCALE_F 144.26950408889634f   // 100 * log2(e)
#define LN2_F   0.6931471805599453f
#define LOG2E_F 1.4426950408889634f
#define GN_F    354.2135193f          // -(256/2) * ln(2*pi*0.01)

typedef __attribute__((ext_vector_type(8))) __bf16 bf16x8;
typedef __attribute__((ext_vector_type(4))) __bf16 bf16x4;
typedef __attribute__((ext_vector_type(4))) float  f32x4;

__device__ __forceinline__ float fexp2(float x) {
#if __has_builtin(__builtin_amdgcn_exp2f)
    return __builtin_amdgcn_exp2f(x);
#else
    return exp2f(x);
#endif
}

__device__ __forceinline__ void async_load16(const void* g, void* l) {
    __builtin_amdgcn_global_load_lds(
        (const __attribute__((address_space(1))) void*)g,
        (__attribute__((address_space(3))) void*)l,
        16, 0, 0);
}

// ---- prep: bf16 conversion + row/col consts + LSE(W) + zero done-counters ----
// one 64-lane wave per row; grid = (B_ROWS + N_PTS) / 4 blocks of 256
__global__ void kde_prep(const float* __restrict__ x, const float* __restrict__ X,
                         const float* __restrict__ W,
                         __bf16* __restrict__ xb, __bf16* __restrict__ Xb,
                         float* __restrict__ rc, float* __restrict__ c2,
                         float* __restrict__ lsew, int* __restrict__ done)
{
    const int wv = blockIdx.x * 4 + (threadIdx.x >> 6);   // row id, 0..24575
    const int l  = threadIdx.x & 63;
    const bool isX = (wv >= B_ROWS);
    const int  r   = isX ? (wv - B_ROWS) : wv;
    const float* src = isX ? X : x;
    const float4 v = ((const float4*)(src + (size_t)r * D_DIM))[l];
    bf16x4 o;
    o[0] = (__bf16)v.x; o[1] = (__bf16)v.y; o[2] = (__bf16)v.z; o[3] = (__bf16)v.w;
    *(bf16x4*)((isX ? Xb : xb) + (size_t)r * D_DIM + l * 4) = o;
    float s = v.x * v.x + v.y * v.y + v.z * v.z + v.w * v.w;
    #pragma unroll
    for (int off = 32; off > 0; off >>= 1) s += __shfl_xor(s, off);
    if (l == 0) {
        if (isX) c2[r] = (W[r] - 50.0f * s) * LOG2E_F;
        else     rc[r] = GN_F - 50.0f * s;
    }

    if (blockIdx.x == 1 && threadIdx.x < BTILES) done[threadIdx.x] = 0;

    if (blockIdx.x == 0) {   // block 0 additionally computes LSE(W)
        const int t = threadIdx.x;
        __shared__ float smw[4];
        __shared__ float bcast;
        float m = -INFINITY;
        for (int i = 0; i < 64; ++i) m = fmaxf(m, W[t + i * 256]);
        #pragma unroll
        for (int off = 32; off > 0; off >>= 1) m = fmaxf(m, __shfl_xor(m, off));
        if ((t & 63) == 0) smw[t >> 6] = m;
        __syncthreads();
        if (t == 0) bcast = fmaxf(fmaxf(smw[0], smw[1]), fmaxf(smw[2], smw[3]));
        __syncthreads();
        const float M = bcast;
        float ss = 0.f;
        for (int i = 0; i < 64; ++i) ss += __expf(W[t + i * 256] - M);
        #pragma unroll
        for (int off = 32; off > 0; off >>= 1) ss += __shfl_xor(ss, off);
        if ((t & 63) == 0) smw[t >> 6] = ss;
        __syncthreads();
        if (t == 0) lsew[0] = M + __logf(smw[0] + smw[1] + smw[2] + smw[3]);
    }
}

// ---- main: dbuf-LDS bf16 MFMA GEMM + fused online log2-LSE + fenced tail combine ----
__global__ __launch_bounds__(256, 2) void kde_gemm(
    const __bf16* __restrict__ xb, const __bf16* __restrict__ Xb,
    const float* __restrict__ c2, const float* __restrict__ rc,
    const float* __restrict__ lsew,
    float* __restrict__ pm, float* __restrict__ ps,
    int* __restrict__ done, float* __restrict__ out)
{
    __shared__ __align__(16) __bf16 As[2][BM * BK];   // 2 x 8 KB
    __shared__ __align__(16) __bf16 Bs[2][BN * BK];   // 2 x 8 KB
    __shared__ float redM[2][BM];
    __shared__ float redS[2][BM];
    __shared__ int lastFlag;

    const int tid  = threadIdx.x;
    const int bid  = blockIdx.x;
    const int lane = tid & 63;
    const int w    = tid >> 6;
    const int wy   = w >> 1;
    const int wx   = w & 1;
    const int l15  = lane & 15;
    const int quad = lane >> 4;

    const int chunk = bid & (NSPLIT - 1);   // XCD-pinned: chunk%8 == bid%8
    const int btile = bid >> 4;
    const int b0    = btile * BM;
    const int nbase = chunk * CHUNK;

    // staging: chunk c = a*256 + tid -> row c>>2, 16B k-chunk c&3 (R1-proven mapping)
    const int kcs  = tid & 3;
    const int srow = tid >> 2;
    const __bf16* aP = xb + (size_t)(b0 + srow) * D_DIM + kcs * 8;
    const __bf16* bP = Xb + (size_t)(nbase + srow) * D_DIM + kcs * 8;
    const int ldsOff0 = (w * 64) * 8;          // wave-uniform LDS element bases
    const int ldsOff1 = (256 + w * 64) * 8;

    // fragment read addresses (elements)
    const int caA = (wy * 64 + l15) * BK + quad * 8;
    const int caB = (wx * 64 + l15) * BK + quad * 8;

    float m_[4][4], s_[4][4];
    #pragma unroll
    for (int i = 0; i < 4; ++i)
        #pragma unroll
        for (int r = 0; r < 4; ++r) { m_[i][r] = -INFINITY; s_[i][r] = 0.0f; }

#define STAGE(buf, aoff, boff) do {                                   \
        async_load16(aP + (aoff), &As[buf][ldsOff0]);                 \
        async_load16(aP + (size_t)64 * D_DIM + (aoff), &As[buf][ldsOff1]); \
        async_load16(bP + (boff), &Bs[buf][ldsOff0]);                 \
        async_load16(bP + (size_t)64 * D_DIM + (boff), &Bs[buf][ldsOff1]); \
    } while (0)

    STAGE(0, 0, 0);   // prologue: (nt=0, kt=0) -> buf 0

    for (int nt = 0; nt < NTILES; ++nt) {
        const int n0 = nbase + nt * BN;
        float c2v[4];
        #pragma unroll
        for (int j = 0; j < 4; ++j)
            c2v[j] = c2[n0 + wx * 64 + j * 16 + l15];

        f32x4 acc[4][4];
        #pragma unroll
        for (int i = 0; i < 4; ++i)
            #pragma unroll
            for (int j = 0; j < 4; ++j) {
                f32x4 z = {0.f, 0.f, 0.f, 0.f};
                acc[i][j] = z;
            }

        #pragma unroll
        for (int kt = 0; kt < KSTEPS; ++kt) {
            // barrier: buf(kt&1) staged+visible; previous buf's readers all done
            __syncthreads();
            if (kt < KSTEPS - 1) {
                STAGE((kt + 1) & 1, (kt + 1) * BK,
                      (size_t)nt * BN * D_DIM + (kt + 1) * BK);
            } else if (nt < NTILES - 1) {
                // KSTEPS even -> next ntile's kt=0 lands back in buf 0
                STAGE(0, 0, (size_t)(nt + 1) * BN * D_DIM);
            }
            const __bf16* Ab = &As[kt & 1][0];
            const __bf16* Bb = &Bs[kt & 1][0];
            bf16x8 af[4], bfr[4];
            #pragma unroll
            for (int i = 0; i < 4; ++i) af[i]  = *(const bf16x8*)&Ab[caA + i * 16 * BK];
            #pragma unroll
            for (int j = 0; j < 4; ++j) bfr[j] = *(const bf16x8*)&Bb[caB + j * 16 * BK];
            #pragma unroll
            for (int i = 0; i < 4; ++i)
                #pragma unroll
                for (int j = 0; j < 4; ++j)
                    acc[i][j] = __builtin_amdgcn_mfma_f32_16x16x32_bf16(af[i], bfr[j], acc[i][j], 0, 0, 0);
        }

        // fused epilogue (overlaps the already-issued next-ntile staging loads)
        #pragma unroll
        for (int i = 0; i < 4; ++i) {
            #pragma unroll
            for (int r = 0; r < 4; ++r) {
                float v0 = fmaf(SCALE_F, acc[i][0][r], c2v[0]);
                float v1 = fmaf(SCALE_F, acc[i][1][r], c2v[1]);
                float v2 = fmaf(SCALE_F, acc[i][2][r], c2v[2]);
                float v3 = fmaf(SCALE_F, acc[i][3][r], c2v[3]);
                float tm = fmaxf(fmaxf(v0, v1), fmaxf(v2, v3));
                float om = m_[i][r];
                float nm = fmaxf(om, tm);
                float e  = fexp2(v0 - nm) + fexp2(v1 - nm) + fexp2(v2 - nm) + fexp2(v3 - nm);
                s_[i][r] = fmaf(s_[i][r], fexp2(om - nm), e);
                m_[i][r] = nm;
            }
        }
    }
#undef STAGE

    // reduce (m,s) across the 16 lanes sharing each row, then across wx waves
    #pragma unroll
    for (int i = 0; i < 4; ++i) {
        #pragma unroll
        for (int r = 0; r < 4; ++r) {
            float mm = m_[i][r], ss = s_[i][r];
            #pragma unroll
            for (int off = 1; off < 16; off <<= 1) {
                float om = __shfl_xor(mm, off);
                float os = __shfl_xor(ss, off);
                float nm = fmaxf(mm, om);
                ss = ss * fexp2(mm - nm) + os * fexp2(om - nm);
                mm = nm;
            }
            if (l15 == 0) {
                int row = wy * 64 + i * 16 + quad * 4 + r;
                redM[wx][row] = mm;
                redS[wx][row] = ss;
            }
        }
    }
    __syncthreads();
    if (tid < BM) {
        float m0 = redM[0][tid], m1 = redM[1][tid];
        float s0 = redS[0][tid], s1 = redS[1][tid];
        float M = fmaxf(m0, m1);
        float S = s0 * fexp2(m0 - M) + s1 * fexp2(m1 - M);
        pm[(size_t)(b0 + tid) * NSPLIT + chunk] = M;
        ps[(size_t)(b0 + tid) * NSPLIT + chunk] = S;
    }

    // ---- fenced tail combine: last chunk-block of this b-tile finishes the rows ----
    __syncthreads();                      // pm/ps stores issued block-wide
    if (tid == 0) {
        __threadfence();                  // release: flush this XCD's L2 writes
        lastFlag = (atomicAdd(&done[btile], 1) == NSPLIT - 1);
    }
    __syncthreads();
    if (lastFlag) {
        __threadfence();                  // acquire: invalidate stale L1/L2 lines
        if (tid < BM) {
            const int b = b0 + tid;
            float pmv[NSPLIT];
            float M = -INFINITY;
            #pragma unroll
            for (int c = 0; c < NSPLIT; ++c) {
                pmv[c] = pm[(size_t)b * NSPLIT + c];
                M = fmaxf(M, pmv[c]);
            }
            float S = 0.f;
            #pragma unroll
            for (int c = 0; c < NSPLIT; ++c)
                S += ps[(size_t)b * NSPLIT + c] * fexp2(pmv[c] - M);
            out[b] = (M + log2f(S)) * LN2_F + rc[b] - lsew[0];
        }
    }
}

extern "C" void kernel_launch(void* const* d_in, const int* in_sizes, int n_in,
                              void* d_out, int out_size, void* d_ws, size_t ws_size,
                              hipStream_t stream)
{
    const float* x = (const float*)d_in[0];
    const float* X = (const float*)d_in[1];
    const float* W = (const float*)d_in[2];
    float* out = (float*)d_out;

    char* ws = (char*)d_ws;
    size_t off = 0;
    __bf16* xb = (__bf16*)(ws + off); off += (size_t)B_ROWS * D_DIM * 2;   // 4 MB
    __bf16* Xb = (__bf16*)(ws + off); off += (size_t)N_PTS  * D_DIM * 2;   // 8 MB
    float* rc   = (float*)(ws + off); off += (size_t)B_ROWS * 4;
    float* c2   = (float*)(ws + off); off += (size_t)N_PTS * 4;
    float* lsew = (float*)(ws + off); off += 256;
    float* pm   = (float*)(ws + off); off += (size_t)B_ROWS * NSPLIT * 4;
    float* ps   = (float*)(ws + off); off += (size_t)B_ROWS * NSPLIT * 4;
    int*   done = (int*)(ws + off);   off += BTILES * sizeof(int);

    kde_prep<<<(B_ROWS + N_PTS) / 4, 256, 0, stream>>>(x, X, W, xb, Xb, rc, c2, lsew, done);
    kde_gemm<<<GRID_GEMM, 256, 0, stream>>>(xb, Xb, c2, rc, lsew, pm, ps, done, out);
}

// Round 5
// 198.296 us; speedup vs baseline: 1.2590x; 1.2590x over previous
//
#include <hip/hip_runtime.h>
#include <hip/hip_bf16.h>
#include <math.h>

// Problem constants
#define B_ROWS 8192
#define N_PTS  16384
#define D_DIM  256

// GEMM tiling — EXACT R1-proven configuration
#define BM 128
#define BN 128
#define BK 32
#define KSTEPS (D_DIM / BK)       // 8
#define NSPLIT 8
#define CHUNK  (N_PTS / NSPLIT)   // 2048
#define NTILES (CHUNK / BN)       // 16
#define BTILES (B_ROWS / BM)      // 64
#define GRID_GEMM (BTILES * NSPLIT) // 512 = 2 blocks/CU

// Folded constants
#define SCALE_F 144.26950408889634f   // 100 * log2(e)
#define LN2_F   0.6931471805599453f
#define LOG2E_F 1.4426950408889634f
#define GN_F    354.2135193f          // -(256/2) * ln(2*pi*0.01)

typedef __attribute__((ext_vector_type(8))) __bf16 bf16x8;
typedef __attribute__((ext_vector_type(4))) __bf16 bf16x4;
typedef __attribute__((ext_vector_type(4))) float  f32x4;

__device__ __forceinline__ float fexp2(float x) {
#if __has_builtin(__builtin_amdgcn_exp2f)
    return __builtin_amdgcn_exp2f(x);
#else
    return exp2f(x);
#endif
}

__device__ __forceinline__ void async_load16(const void* g, void* l) {
    __builtin_amdgcn_global_load_lds(
        (const __attribute__((address_space(1))) void*)g,
        (__attribute__((address_space(3))) void*)l,
        16, 0, 0);
}

// ---- prep: bf16 conversion + row/col consts + LSE(W) + zero done-counters ----
__global__ void kde_prep(const float* __restrict__ x, const float* __restrict__ X,
                         const float* __restrict__ W,
                         __bf16* __restrict__ xb, __bf16* __restrict__ Xb,
                         float* __restrict__ rc, float* __restrict__ c2,
                         float* __restrict__ lsew, int* __restrict__ done)
{
    const int wv = blockIdx.x * 4 + (threadIdx.x >> 6);   // row id, 0..24575
    const int l  = threadIdx.x & 63;
    const bool isX = (wv >= B_ROWS);
    const int  r   = isX ? (wv - B_ROWS) : wv;
    const float* src = isX ? X : x;
    const float4 v = ((const float4*)(src + (size_t)r * D_DIM))[l];
    bf16x4 o;
    o[0] = (__bf16)v.x; o[1] = (__bf16)v.y; o[2] = (__bf16)v.z; o[3] = (__bf16)v.w;
    *(bf16x4*)((isX ? Xb : xb) + (size_t)r * D_DIM + l * 4) = o;
    float s = v.x * v.x + v.y * v.y + v.z * v.z + v.w * v.w;
    #pragma unroll
    for (int off = 32; off > 0; off >>= 1) s += __shfl_xor(s, off);
    if (l == 0) {
        if (isX) c2[r] = (W[r] - 50.0f * s) * LOG2E_F;
        else     rc[r] = GN_F - 50.0f * s;
    }

    if (blockIdx.x == 1 && threadIdx.x < BTILES) done[threadIdx.x] = 0;

    if (blockIdx.x == 0) {   // block 0 additionally computes LSE(W)
        const int t = threadIdx.x;
        __shared__ float smw[4];
        __shared__ float bcast;
        float m = -INFINITY;
        for (int i = 0; i < 64; ++i) m = fmaxf(m, W[t + i * 256]);
        #pragma unroll
        for (int off = 32; off > 0; off >>= 1) m = fmaxf(m, __shfl_xor(m, off));
        if ((t & 63) == 0) smw[t >> 6] = m;
        __syncthreads();
        if (t == 0) bcast = fmaxf(fmaxf(smw[0], smw[1]), fmaxf(smw[2], smw[3]));
        __syncthreads();
        const float M = bcast;
        float ss = 0.f;
        for (int i = 0; i < 64; ++i) ss += __expf(W[t + i * 256] - M);
        #pragma unroll
        for (int off = 32; off > 0; off >>= 1) ss += __shfl_xor(ss, off);
        if ((t & 63) == 0) smw[t >> 6] = ss;
        __syncthreads();
        if (t == 0) lsew[0] = M + __logf(smw[0] + smw[1] + smw[2] + smw[3]);
    }
}

// ---- main: R1-proven single-buffer MFMA GEMM + fused online log2-LSE
//      + fenced atomic-tail combine (saves the separate combine dispatch) ----
__global__ __launch_bounds__(256, 2) void kde_gemm(
    const __bf16* __restrict__ xb, const __bf16* __restrict__ Xb,
    const float* __restrict__ c2, const float* __restrict__ rc,
    const float* __restrict__ lsew,
    float* __restrict__ pm, float* __restrict__ ps,
    int* __restrict__ done, float* __restrict__ out)
{
    __shared__ __align__(16) __bf16 As[BM * BK];   // 8 KB (single buffer — R1)
    __shared__ __align__(16) __bf16 Bs[BN * BK];   // 8 KB
    __shared__ float redM[2][BM];
    __shared__ float redS[2][BM];
    __shared__ int lastFlag;

    const int tid  = threadIdx.x;
    const int bid  = blockIdx.x;
    const int lane = tid & 63;
    const int w    = tid >> 6;
    const int wy   = w >> 1;
    const int wx   = w & 1;
    const int l15  = lane & 15;
    const int quad = lane >> 4;

    const int chunk = bid & (NSPLIT - 1);   // XCD-pinned chunk
    const int btile = bid >> 3;
    const int b0    = btile * BM;
    const int nbase = chunk * CHUNK;

    // staging: chunk c = a*256 + tid -> row c>>2, 16B k-chunk c&3 (R1-proven mapping)
    const int kcs  = tid & 3;
    const int srow = tid >> 2;
    const __bf16* aptr0 = xb + (size_t)(b0 + srow) * D_DIM + kcs * 8;
    const __bf16* aptr1 = aptr0 + (size_t)64 * D_DIM;
    const __bf16* bp0   = Xb + (size_t)(nbase + srow) * D_DIM + kcs * 8;
    const __bf16* bp1   = bp0 + (size_t)64 * D_DIM;
    const int ldsOff0 = (w * 64) * 8;          // wave-uniform LDS element bases
    const int ldsOff1 = (256 + w * 64) * 8;

    // fragment read addresses (elements)
    const int caA = (wy * 64 + l15) * BK + quad * 8;
    const int caB = (wx * 64 + l15) * BK + quad * 8;

    float m_[4][4], s_[4][4];
    #pragma unroll
    for (int i = 0; i < 4; ++i)
        #pragma unroll
        for (int r = 0; r < 4; ++r) { m_[i][r] = -INFINITY; s_[i][r] = 0.0f; }

    for (int nt = 0; nt < NTILES; ++nt) {
        const int n0 = nbase + nt * BN;
        float c2v[4];
        #pragma unroll
        for (int j = 0; j < 4; ++j)
            c2v[j] = c2[n0 + wx * 64 + j * 16 + l15];

        f32x4 acc[4][4];
        #pragma unroll
        for (int i = 0; i < 4; ++i)
            #pragma unroll
            for (int j = 0; j < 4; ++j) {
                f32x4 z = {0.f, 0.f, 0.f, 0.f};
                acc[i][j] = z;
            }

        #pragma unroll
        for (int kt = 0; kt < KSTEPS; ++kt) {
            const int ko = kt * BK;
            async_load16(aptr0 + ko, &As[ldsOff0]);
            async_load16(aptr1 + ko, &As[ldsOff1]);
            async_load16(bp0 + ko, &Bs[ldsOff0]);
            async_load16(bp1 + ko, &Bs[ldsOff1]);
            __syncthreads();   // drains vmcnt -> tile visible

            bf16x8 af[4], bfr[4];
            #pragma unroll
            for (int i = 0; i < 4; ++i) af[i]  = *(const bf16x8*)&As[caA + i * 16 * BK];
            #pragma unroll
            for (int j = 0; j < 4; ++j) bfr[j] = *(const bf16x8*)&Bs[caB + j * 16 * BK];
            #pragma unroll
            for (int i = 0; i < 4; ++i)
                #pragma unroll
                for (int j = 0; j < 4; ++j)
                    acc[i][j] = __builtin_amdgcn_mfma_f32_16x16x32_bf16(af[i], bfr[j], acc[i][j], 0, 0, 0);
            __syncthreads();   // before next k-step overwrites LDS
        }
        bp0 += (size_t)BN * D_DIM;
        bp1 += (size_t)BN * D_DIM;

        // fused epilogue: online LSE (log2 domain), purely per-lane
        #pragma unroll
        for (int i = 0; i < 4; ++i) {
            #pragma unroll
            for (int r = 0; r < 4; ++r) {
                float v0 = fmaf(SCALE_F, acc[i][0][r], c2v[0]);
                float v1 = fmaf(SCALE_F, acc[i][1][r], c2v[1]);
                float v2 = fmaf(SCALE_F, acc[i][2][r], c2v[2]);
                float v3 = fmaf(SCALE_F, acc[i][3][r], c2v[3]);
                float tm = fmaxf(fmaxf(v0, v1), fmaxf(v2, v3));
                float om = m_[i][r];
                float nm = fmaxf(om, tm);
                float e  = fexp2(v0 - nm) + fexp2(v1 - nm) + fexp2(v2 - nm) + fexp2(v3 - nm);
                s_[i][r] = fmaf(s_[i][r], fexp2(om - nm), e);
                m_[i][r] = nm;
            }
        }
    }

    // reduce (m,s) across the 16 lanes sharing each row, then across wx waves
    #pragma unroll
    for (int i = 0; i < 4; ++i) {
        #pragma unroll
        for (int r = 0; r < 4; ++r) {
            float mm = m_[i][r], ss = s_[i][r];
            #pragma unroll
            for (int off = 1; off < 16; off <<= 1) {
                float om = __shfl_xor(mm, off);
                float os = __shfl_xor(ss, off);
                float nm = fmaxf(mm, om);
                ss = ss * fexp2(mm - nm) + os * fexp2(om - nm);
                mm = nm;
            }
            if (l15 == 0) {
                int row = wy * 64 + i * 16 + quad * 4 + r;
                redM[wx][row] = mm;
                redS[wx][row] = ss;
            }
        }
    }
    __syncthreads();
    if (tid < BM) {
        float m0 = redM[0][tid], m1 = redM[1][tid];
        float s0 = redS[0][tid], s1 = redS[1][tid];
        float M = fmaxf(m0, m1);
        float S = s0 * fexp2(m0 - M) + s1 * fexp2(m1 - M);
        pm[(size_t)(b0 + tid) * NSPLIT + chunk] = M;
        ps[(size_t)(b0 + tid) * NSPLIT + chunk] = S;
    }

    // ---- fenced tail combine: last chunk-block of this b-tile finishes the rows ----
    __syncthreads();                      // pm/ps stores issued block-wide
    if (tid == 0) {
        __threadfence();                  // release
        lastFlag = (atomicAdd(&done[btile], 1) == NSPLIT - 1);
    }
    __syncthreads();
    if (lastFlag) {
        __threadfence();                  // acquire
        if (tid < BM) {
            const int b = b0 + tid;
            float pmv[NSPLIT];
            float M = -INFINITY;
            #pragma unroll
            for (int c = 0; c < NSPLIT; ++c) {
                pmv[c] = pm[(size_t)b * NSPLIT + c];
                M = fmaxf(M, pmv[c]);
            }
            float S = 0.f;
            #pragma unroll
            for (int c = 0; c < NSPLIT; ++c)
                S += ps[(size_t)b * NSPLIT + c] * fexp2(pmv[c] - M);
            out[b] = (M + log2f(S)) * LN2_F + rc[b] - lsew[0];
        }
    }
}

extern "C" void kernel_launch(void* const* d_in, const int* in_sizes, int n_in,
                              void* d_out, int out_size, void* d_ws, size_t ws_size,
                              hipStream_t stream)
{
    const float* x = (const float*)d_in[0];
    const float* X = (const float*)d_in[1];
    const float* W = (const float*)d_in[2];
    float* out = (float*)d_out;

    char* ws = (char*)d_ws;
    size_t off = 0;
    __bf16* xb = (__bf16*)(ws + off); off += (size_t)B_ROWS * D_DIM * 2;   // 4 MB
    __bf16* Xb = (__bf16*)(ws + off); off += (size_t)N_PTS  * D_DIM * 2;   // 8 MB
    float* rc   = (float*)(ws + off); off += (size_t)B_ROWS * 4;
    float* c2   = (float*)(ws + off); off += (size_t)N_PTS * 4;
    float* lsew = (float*)(ws + off); off += 256;
    float* pm   = (float*)(ws + off); off += (size_t)B_ROWS * NSPLIT * 4;
    float* ps   = (float*)(ws + off); off += (size_t)B_ROWS * NSPLIT * 4;
    int*   done = (int*)(ws + off);   off += BTILES * sizeof(int);

    kde_prep<<<(B_ROWS + N_PTS) / 4, 256, 0, stream>>>(x, X, W, xb, Xb, rc, c2, lsew, done);
    kde_gemm<<<GRID_GEMM, 256, 0, stream>>>(xb, Xb, c2, rc, lsew, pm, ps, done, out);
}

// Round 6
// 193.172 us; speedup vs baseline: 1.2924x; 1.0265x over previous
//
#include <hip/hip_runtime.h>
#include <hip/hip_bf16.h>
#include <math.h>

// Problem constants
#define B_ROWS 8192
#define N_PTS  16384
#define D_DIM  256

// GEMM tiling: A held in registers (whole K), only B staged through LDS.
#define BM 128
#define BN 64
#define NSPLIT 8
#define CHUNK  (N_PTS / NSPLIT)   // 2048
#define NTILES (CHUNK / BN)       // 32
#define BTILES (B_ROWS / BM)      // 64
#define GRID_GEMM (BTILES * NSPLIT) // 512 = 2 blocks/CU

// Folded constants
#define SCALE_F 144.26950408889634f   // 100 * log2(e)
#define LN2_F   0.6931471805599453f
#define LOG2E_F 1.4426950408889634f
#define GN_F    354.2135193f          // -(256/2) * ln(2*pi*0.01)

typedef __attribute__((ext_vector_type(8))) __bf16 bf16x8;
typedef __attribute__((ext_vector_type(4))) __bf16 bf16x4;
typedef __attribute__((ext_vector_type(4))) float  f32x4;

__device__ __forceinline__ float fexp2(float x) {
#if __has_builtin(__builtin_amdgcn_exp2f)
    return __builtin_amdgcn_exp2f(x);
#else
    return exp2f(x);
#endif
}

__device__ __forceinline__ void async_load16(const void* g, void* l) {
    __builtin_amdgcn_global_load_lds(
        (const __attribute__((address_space(1))) void*)g,
        (__attribute__((address_space(3))) void*)l,
        16, 0, 0);
}

// ---- prep: bf16 conversion + row/col consts + LSE(W) + zero done-counters ----
__global__ void kde_prep(const float* __restrict__ x, const float* __restrict__ X,
                         const float* __restrict__ W,
                         __bf16* __restrict__ xb, __bf16* __restrict__ Xb,
                         float* __restrict__ rc, float* __restrict__ c2,
                         float* __restrict__ lsew, int* __restrict__ done)
{
    const int wv = blockIdx.x * 4 + (threadIdx.x >> 6);   // row id, 0..24575
    const int l  = threadIdx.x & 63;
    const bool isX = (wv >= B_ROWS);
    const int  r   = isX ? (wv - B_ROWS) : wv;
    const float* src = isX ? X : x;
    const float4 v = ((const float4*)(src + (size_t)r * D_DIM))[l];
    bf16x4 o;
    o[0] = (__bf16)v.x; o[1] = (__bf16)v.y; o[2] = (__bf16)v.z; o[3] = (__bf16)v.w;
    *(bf16x4*)((isX ? Xb : xb) + (size_t)r * D_DIM + l * 4) = o;
    float s = v.x * v.x + v.y * v.y + v.z * v.z + v.w * v.w;
    #pragma unroll
    for (int off = 32; off > 0; off >>= 1) s += __shfl_xor(s, off);
    if (l == 0) {
        if (isX) c2[r] = (W[r] - 50.0f * s) * LOG2E_F;
        else     rc[r] = GN_F - 50.0f * s;
    }

    if (blockIdx.x == 1 && threadIdx.x < BTILES) done[threadIdx.x] = 0;

    if (blockIdx.x == 0) {   // block 0 additionally computes LSE(W)
        const int t = threadIdx.x;
        __shared__ float smw[4];
        __shared__ float bcast;
        float m = -INFINITY;
        for (int i = 0; i < 64; ++i) m = fmaxf(m, W[t + i * 256]);
        #pragma unroll
        for (int off = 32; off > 0; off >>= 1) m = fmaxf(m, __shfl_xor(m, off));
        if ((t & 63) == 0) smw[t >> 6] = m;
        __syncthreads();
        if (t == 0) bcast = fmaxf(fmaxf(smw[0], smw[1]), fmaxf(smw[2], smw[3]));
        __syncthreads();
        const float M = bcast;
        float ss = 0.f;
        for (int i = 0; i < 64; ++i) ss += __expf(W[t + i * 256] - M);
        #pragma unroll
        for (int off = 32; off > 0; off >>= 1) ss += __shfl_xor(ss, off);
        if ((t & 63) == 0) smw[t >> 6] = ss;
        __syncthreads();
        if (t == 0) lsew[0] = M + __logf(smw[0] + smw[1] + smw[2] + smw[3]);
    }
}

// ---- main: A-in-registers MFMA GEMM + fused online log2-LSE + fenced tail ----
// Each wave holds its full 64-row x 256-K A panel in 128 VGPRs (loaded once,
// L2-hot). K-loop stages only B: two 64x32 sub-tiles (8 KB) per barrier pair,
// 16 MFMA between barriers. LDS traffic/work-unit: 48 KB -> 24 KB.
__global__ __launch_bounds__(256, 2) void kde_gemm(
    const __bf16* __restrict__ xb, const __bf16* __restrict__ Xb,
    const float* __restrict__ c2, const float* __restrict__ rc,
    const float* __restrict__ lsew,
    float* __restrict__ pm, float* __restrict__ ps,
    int* __restrict__ done, float* __restrict__ out)
{
    __shared__ __align__(16) __bf16 Bs[2 * BN * 32];   // two 64x32 sub-tiles, 8 KB
    __shared__ float redM[2][BM];
    __shared__ float redS[2][BM];
    __shared__ int lastFlag;

    const int tid  = threadIdx.x;
    const int lane = tid & 63;
    const int w    = tid >> 6;
    const int wy   = w >> 1;           // 0,1: 64-row half of A
    const int wx   = w & 1;            // 0,1: 32-col half of B tile
    const int l15  = lane & 15;
    const int quad = lane >> 4;

    const int btile = blockIdx.x;      // R1-proven mapping: x = btile (fastest)
    const int chunk = blockIdx.y;
    const int b0    = btile * BM;
    const int nbase = chunk * CHUNK;

    // ---- load this wave's full A panel into registers: 64 rows x 256 K ----
    bf16x8 afr[4][8];                  // [16-row group][32-K group] = 128 VGPRs
    {
        const __bf16* abase = xb + (size_t)(b0 + wy * 64 + l15) * D_DIM + quad * 8;
        #pragma unroll
        for (int i = 0; i < 4; ++i)
            #pragma unroll
            for (int kt = 0; kt < 8; ++kt)
                afr[i][kt] = *(const bf16x8*)(abase + (size_t)i * 16 * D_DIM + kt * 32);
    }

    // ---- B staging addressing (R1-proven 64B-row-stride layout per sub-tile) ----
    const int srow = tid >> 2;         // 0..63
    const int kc   = tid & 3;          // 16B chunk within 32-K row
    const __bf16* bpt = Xb + (size_t)(nbase + srow) * D_DIM + kc * 8;
    const int ldsT0 = (w * 64) * 8;           // sub-tile 0, wave-uniform elem base
    const int ldsT1 = 2048 + (w * 64) * 8;    // sub-tile 1

    // fragment read base (elements): row = wx*32 + j*16 + l15, chunk = quad
    const int caB = (wx * 32 + l15) * 32 + quad * 8;   // + j*512 + t*2048

    float m_[4][4], s_[4][4];
    #pragma unroll
    for (int i = 0; i < 4; ++i)
        #pragma unroll
        for (int r = 0; r < 4; ++r) { m_[i][r] = -INFINITY; s_[i][r] = 0.0f; }

    #pragma unroll 1
    for (int nt = 0; nt < NTILES; ++nt) {
        const int n0 = nbase + nt * BN;
        float c2v0 = c2[n0 + wx * 32 + l15];
        float c2v1 = c2[n0 + wx * 32 + 16 + l15];

        f32x4 acc[4][2];
        #pragma unroll
        for (int i = 0; i < 4; ++i)
            #pragma unroll
            for (int j = 0; j < 2; ++j) {
                f32x4 z = {0.f, 0.f, 0.f, 0.f};
                acc[i][j] = z;
            }

        #pragma unroll
        for (int ks = 0; ks < 4; ++ks) {           // 64 K per barrier pair
            async_load16(bpt + ks * 64,      &Bs[ldsT0]);
            async_load16(bpt + ks * 64 + 32, &Bs[ldsT1]);
            __syncthreads();   // drains vmcnt -> both sub-tiles visible

            bf16x8 b00 = *(const bf16x8*)&Bs[caB];
            bf16x8 b01 = *(const bf16x8*)&Bs[caB + 512];
            bf16x8 b10 = *(const bf16x8*)&Bs[caB + 2048];
            bf16x8 b11 = *(const bf16x8*)&Bs[caB + 2048 + 512];
            #pragma unroll
            for (int i = 0; i < 4; ++i) {
                acc[i][0] = __builtin_amdgcn_mfma_f32_16x16x32_bf16(afr[i][ks * 2],     b00, acc[i][0], 0, 0, 0);
                acc[i][1] = __builtin_amdgcn_mfma_f32_16x16x32_bf16(afr[i][ks * 2],     b01, acc[i][1], 0, 0, 0);
                acc[i][0] = __builtin_amdgcn_mfma_f32_16x16x32_bf16(afr[i][ks * 2 + 1], b10, acc[i][0], 0, 0, 0);
                acc[i][1] = __builtin_amdgcn_mfma_f32_16x16x32_bf16(afr[i][ks * 2 + 1], b11, acc[i][1], 0, 0, 0);
            }
            __syncthreads();   // before next stage overwrites Bs
        }
        bpt += (size_t)BN * D_DIM;

        // fused epilogue: online LSE (log2 domain), purely per-lane
        #pragma unroll
        for (int i = 0; i < 4; ++i) {
            #pragma unroll
            for (int r = 0; r < 4; ++r) {
                float v0 = fmaf(SCALE_F, acc[i][0][r], c2v0);
                float v1 = fmaf(SCALE_F, acc[i][1][r], c2v1);
                float tm = fmaxf(v0, v1);
                float om = m_[i][r];
                float nm = fmaxf(om, tm);
                float e  = fexp2(v0 - nm) + fexp2(v1 - nm);
                s_[i][r] = fmaf(s_[i][r], fexp2(om - nm), e);
                m_[i][r] = nm;
            }
        }
    }

    // reduce (m,s) across the 16 lanes sharing each row, then across wx waves
    #pragma unroll
    for (int i = 0; i < 4; ++i) {
        #pragma unroll
        for (int r = 0; r < 4; ++r) {
            float mm = m_[i][r], ss = s_[i][r];
            #pragma unroll
            for (int off = 1; off < 16; off <<= 1) {
                float om = __shfl_xor(mm, off);
                float os = __shfl_xor(ss, off);
                float nm = fmaxf(mm, om);
                ss = ss * fexp2(mm - nm) + os * fexp2(om - nm);
                mm = nm;
            }
            if (l15 == 0) {
                int row = wy * 64 + i * 16 + quad * 4 + r;
                redM[wx][row] = mm;
                redS[wx][row] = ss;
            }
        }
    }
    __syncthreads();
    if (tid < BM) {
        float m0 = redM[0][tid], m1 = redM[1][tid];
        float s0 = redS[0][tid], s1 = redS[1][tid];
        float M = fmaxf(m0, m1);
        float S = s0 * fexp2(m0 - M) + s1 * fexp2(m1 - M);
        pm[(size_t)(b0 + tid) * NSPLIT + chunk] = M;
        ps[(size_t)(b0 + tid) * NSPLIT + chunk] = S;
    }

    // ---- fenced tail combine: last chunk-block of this b-tile finishes the rows ----
    __syncthreads();                      // pm/ps stores issued block-wide
    if (tid == 0) {
        __threadfence();                  // release
        lastFlag = (atomicAdd(&done[btile], 1) == NSPLIT - 1);
    }
    __syncthreads();
    if (lastFlag) {
        __threadfence();                  // acquire
        if (tid < BM) {
            const int b = b0 + tid;
            float pmv[NSPLIT];
            float M = -INFINITY;
            #pragma unroll
            for (int c = 0; c < NSPLIT; ++c) {
                pmv[c] = pm[(size_t)b * NSPLIT + c];
                M = fmaxf(M, pmv[c]);
            }
            float S = 0.f;
            #pragma unroll
            for (int c = 0; c < NSPLIT; ++c)
                S += ps[(size_t)b * NSPLIT + c] * fexp2(pmv[c] - M);
            out[b] = (M + log2f(S)) * LN2_F + rc[b] - lsew[0];
        }
    }
}

extern "C" void kernel_launch(void* const* d_in, const int* in_sizes, int n_in,
                              void* d_out, int out_size, void* d_ws, size_t ws_size,
                              hipStream_t stream)
{
    const float* x = (const float*)d_in[0];
    const float* X = (const float*)d_in[1];
    const float* W = (const float*)d_in[2];
    float* out = (float*)d_out;

    char* ws = (char*)d_ws;
    size_t off = 0;
    __bf16* xb = (__bf16*)(ws + off); off += (size_t)B_ROWS * D_DIM * 2;   // 4 MB
    __bf16* Xb = (__bf16*)(ws + off); off += (size_t)N_PTS  * D_DIM * 2;   // 8 MB
    float* rc   = (float*)(ws + off); off += (size_t)B_ROWS * 4;
    float* c2   = (float*)(ws + off); off += (size_t)N_PTS * 4;
    float* lsew = (float*)(ws + off); off += 256;
    float* pm   = (float*)(ws + off); off += (size_t)B_ROWS * NSPLIT * 4;
    float* ps   = (float*)(ws + off); off += (size_t)B_ROWS * NSPLIT * 4;
    int*   done = (int*)(ws + off);   off += BTILES * sizeof(int);

    kde_prep<<<(B_ROWS + N_PTS) / 4, 256, 0, stream>>>(x, X, W, xb, Xb, rc, c2, lsew, done);
    kde_gemm<<<dim3(BTILES, NSPLIT), 256, 0, stream>>>(xb, Xb, c2, rc, lsew, pm, ps, done, out);
}